// Round 4
// baseline (232.262 us; speedup 1.0000x reference)
//
#include <hip/hip_runtime.h>
#include <math.h>

#define NROWS 2400
#define NCLS  91
#define L     128
#define KSUB  23
#define NKEEP 256

typedef float vfloat4 __attribute__((ext_vector_type(4)));   // clang-native, NT-store OK

// ---------------------------------------------------------------------------
// Setup kernel, grid 10 x 256:
//  - block 0 additionally builds Csub[23][128] into d_ws using the EXACT
//    double-precision math of the original passing kernel (bit-identical).
//  - every thread handles one row's scores/labels/boxes.
// ---------------------------------------------------------------------------
__global__ void __launch_bounds__(256)
setup_kernel(const float* __restrict__ logits,
             const float* __restrict__ pboxes,
             const int*   __restrict__ tsz,
             float* __restrict__ csub,
             float* __restrict__ out)
{
    const int tid = threadIdx.x;

    if (blockIdx.x == 0) {
        __shared__ double tab[512];
        for (int t = tid; t < 512; t += 256)
            tab[t] = cos((3.14159265358979323846 / 256.0) * (double)t);
        __syncthreads();
        const double s0 = sqrt(1.0 / 128.0);
        for (int idx = tid; idx < KSUB * L; idx += 256) {
            const int u = idx >> 7, m = idx & 127;
            float v;
            if (u == 0) v = (float)s0;
            else        v = (float)(0.125 * tab[((2 * m + 1) * u) & 511]);
            csub[idx] = v;
        }
    }

    const int row = blockIdx.x * 256 + tid;
    if (row < NROWS) {
        const float* lrow = logits + (size_t)row * NCLS;
        float best = 1.0f / (1.0f + expf(-lrow[0]));
        int   bi = 0;
        for (int c = 1; c < NCLS; ++c) {
            const float p = 1.0f / (1.0f + expf(-lrow[c]));
            if (p > best) { best = p; bi = c; }        // strict > keeps first index
        }
        out[row] = best;                                // scores
        out[NROWS + row] = (float)bi;                   // labels

        const int b = row / 300;
        const float W = (float)tsz[2 * b + 1];
        const float H = (float)tsz[2 * b + 0];
        const float4 bx = *(const float4*)(pboxes + (size_t)row * 4);
        float4 o;
        o.x = (bx.x - 0.5f * bx.z) * W;
        o.y = (bx.y - 0.5f * bx.w) * H;
        o.z = (bx.x + 0.5f * bx.z) * W;
        o.w = (bx.y + 0.5f * bx.w) * H;
        *(float4*)(out + 2 * NROWS + (size_t)row * 4) = o;
    }
}

// LDS float layout (mask kernel):
// [0, 2944)      Csub[23][128]
// [2944, 5888)   M1t[23][128]
// [5888, 6440)   coef[23][24]
// [6440, 6448)   min/max reduce scratch
#define COEF_OFF 5888
#define RED_OFF  6440
#define SMEM_FLOATS 6448

__global__ void __launch_bounds__(256, 4)   // cap VGPRs at 128 -> 4 waves/SIMD
mask_kernel(const float* __restrict__ vecs,
            const float* __restrict__ csub_g,
            float* __restrict__ out)
{
    __shared__ float smem[SMEM_FLOATS];
    const int br  = blockIdx.x;
    const int tid = threadIdx.x;

    // ---------- staging: Csub global->LDS, coef zero+scatter, one barrier ----------
    for (int t = tid; t < 736; t += 256)
        ((float4*)smem)[t] = ((const float4*)csub_g)[t];

    float* coef = &smem[COEF_OFF];
    for (int t = tid; t < KSUB * 24; t += 256) {
        const int u = t / 24, v = t - u * 24;
        const int s = u + v;
        if (v == 23 || s > 22 || (s == 22 && u < 20)) coef[t] = 0.0f;
    }
    {
        const int k = tid;
        int s = 0;
        while ((s + 1) * (s + 2) / 2 <= k) ++s;
        const int r = k - s * (s + 1) / 2;
        const int u  = (s & 1) ? r : (s - r);
        const int vv = (s & 1) ? (s - r) : r;
        coef[u * 24 + vv] = vecs[(size_t)br * NKEEP + k];
    }
    __syncthreads();

    // ---------- Part D: M1t[v][i] = sum_u Csub[u][i]*coef[u][v] ----------
    float* M1 = &smem[2944];
    {
        const int i = tid & 127;
        float cs[KSUB];
        #pragma unroll
        for (int u = 0; u < KSUB; ++u) cs[u] = smem[u * L + i];
        if (tid < 128) {
            #pragma unroll
            for (int v = 0; v < 12; ++v) {
                float a = 0.0f;
                #pragma unroll
                for (int u = 0; u < KSUB; ++u) a += cs[u] * coef[u * 24 + v];
                M1[v * L + i] = a;
            }
        } else {
            #pragma unroll
            for (int v = 12; v < KSUB; ++v) {
                float a = 0.0f;
                #pragma unroll
                for (int u = 0; u < KSUB; ++u) a += cs[u] * coef[u * 24 + v];
                M1[v * L + i] = a;
            }
        }
    }
    __syncthreads();

    // ---------- Part E: re[i][j] = sum_v M1t[v][i]*Csub[v][j], low-register form ----------
    const int tx = tid & 31, ty = tid >> 5;
    const int j0 = tx << 2, i0 = ty << 4;
    float acc[16][4];
    #pragma unroll
    for (int r = 0; r < 16; ++r)
        #pragma unroll
        for (int q = 0; q < 4; ++q) acc[r][q] = 0.0f;

    for (int v = 0; v < KSUB; ++v) {
        const float4 c = *(const float4*)&smem[v * L + j0];
        #pragma unroll
        for (int g = 0; g < 4; ++g) {
            const float4 m = *(const float4*)&M1[v * L + i0 + 4 * g];
            acc[4*g+0][0] += m.x * c.x; acc[4*g+0][1] += m.x * c.y;
            acc[4*g+0][2] += m.x * c.z; acc[4*g+0][3] += m.x * c.w;
            acc[4*g+1][0] += m.y * c.x; acc[4*g+1][1] += m.y * c.y;
            acc[4*g+1][2] += m.y * c.z; acc[4*g+1][3] += m.y * c.w;
            acc[4*g+2][0] += m.z * c.x; acc[4*g+2][1] += m.z * c.y;
            acc[4*g+2][2] += m.z * c.z; acc[4*g+2][3] += m.z * c.w;
            acc[4*g+3][0] += m.w * c.x; acc[4*g+3][1] += m.w * c.y;
            acc[4*g+3][2] += m.w * c.z; acc[4*g+3][3] += m.w * c.w;
        }
    }

    // ---------- min/max reduce -> threshold ----------
    float mn = acc[0][0], mx = acc[0][0];
    #pragma unroll
    for (int r = 0; r < 16; ++r)
        #pragma unroll
        for (int q = 0; q < 4; ++q) {
            mn = fminf(mn, acc[r][q]);
            mx = fmaxf(mx, acc[r][q]);
        }
    #pragma unroll
    for (int off = 32; off > 0; off >>= 1) {
        mn = fminf(mn, __shfl_xor(mn, off, 64));
        mx = fmaxf(mx, __shfl_xor(mx, off, 64));
    }
    const int w = tid >> 6;
    if ((tid & 63) == 0) { smem[RED_OFF + w] = mn; smem[RED_OFF + 4 + w] = mx; }
    __syncthreads();
    const float gmn = fminf(fminf(smem[RED_OFF + 0], smem[RED_OFF + 1]),
                            fminf(smem[RED_OFF + 2], smem[RED_OFF + 3]));
    const float gmx = fmaxf(fmaxf(smem[RED_OFF + 4], smem[RED_OFF + 5]),
                            fmaxf(smem[RED_OFF + 6], smem[RED_OFF + 7]));
    const float thr = (gmx + gmn) * 0.5f;

    // ---------- binarize + nontemporal coalesced float4 stores ----------
    float* omask = out + 6 * NROWS + (size_t)br * (L * L);
    #pragma unroll
    for (int r = 0; r < 16; ++r) {
        vfloat4 o;
        o.x = acc[r][0] > thr ? 1.0f : 0.0f;
        o.y = acc[r][1] > thr ? 1.0f : 0.0f;
        o.z = acc[r][2] > thr ? 1.0f : 0.0f;
        o.w = acc[r][3] > thr ? 1.0f : 0.0f;
        __builtin_nontemporal_store(o, (vfloat4*)&omask[(i0 + r) * L + j0]);
    }
}

extern "C" void kernel_launch(void* const* d_in, const int* in_sizes, int n_in,
                              void* d_out, int out_size, void* d_ws, size_t ws_size,
                              hipStream_t stream)
{
    const float* logits = (const float*)d_in[0];
    const float* pboxes = (const float*)d_in[1];
    const float* vecs   = (const float*)d_in[2];
    const int*   tsz    = (const int*)d_in[3];
    float* out  = (float*)d_out;
    float* csub = (float*)d_ws;                 // 2944 floats = 11.8 KB scratch
    (void)in_sizes; (void)n_in; (void)out_size; (void)ws_size;

    setup_kernel<<<dim3(10),    dim3(256), 0, stream>>>(logits, pboxes, tsz, csub, out);
    mask_kernel <<<dim3(NROWS), dim3(256), 0, stream>>>(vecs, csub, out);
}

// Round 5
// 190.965 us; speedup vs baseline: 1.2163x; 1.2163x over previous
//
#include <hip/hip_runtime.h>
#include <math.h>

#define NROWS 2400
#define NCLS  91
#define L     128
#define KSUB  23
#define NKEEP 256

// LDS float layout:
// [0, 2944)      Csub[23][128]
// [2944, 5888)   phase 1: double tab[512]  (occupies [2944,3968))
//                phase 2+: M1t[23][128]    (M1t[v][i] = sum_u Csub[u][i]*coef[u][v])
// [5888, 6440)   coef[23][24]
// [6440, 6448)   min/max reduce scratch
#define TAB_OFF  2944
#define M1_OFF   2944
#define COEF_OFF 5888
#define RED_OFF  6440
#define SMEM_FLOATS 6448

__global__ void __launch_bounds__(256)
postproc_kernel(const float* __restrict__ logits,
                const float* __restrict__ pboxes,
                const float* __restrict__ vecs,
                const int*   __restrict__ tsz,
                float* __restrict__ out)
{
    __shared__ float smem[SMEM_FLOATS];
    const int br  = blockIdx.x;
    const int tid = threadIdx.x;

    // ---------- Part A: scores / labels / boxes (wave 0 only, no barriers) ----------
    if (tid < 64) {
        const float* lrow = logits + (size_t)br * NCLS;
        float p = 1.0f / (1.0f + expf(-lrow[tid]));   // tid < 64 < 91: always valid
        int   bi = tid;
        if (tid < NCLS - 64) {                         // classes 64..90
            float p2 = 1.0f / (1.0f + expf(-lrow[tid + 64]));
            if (p2 > p) { p = p2; bi = tid + 64; }    // tie -> keep lower index
        }
        #pragma unroll
        for (int off = 32; off > 0; off >>= 1) {
            float po = __shfl_xor(p, off, 64);
            int   io = __shfl_xor(bi, off, 64);
            if (po > p || (po == p && io < bi)) { p = po; bi = io; }
        }
        if (tid == 0) {
            out[br] = p;                               // scores
            out[NROWS + br] = (float)bi;               // labels
            const int b = br / 300;
            const float W = (float)tsz[2 * b + 1];
            const float H = (float)tsz[2 * b + 0];
            const float4 bx = *(const float4*)(pboxes + (size_t)br * 4);
            float4 o;
            o.x = (bx.x - 0.5f * bx.z) * W;
            o.y = (bx.y - 0.5f * bx.w) * H;
            o.z = (bx.x + 0.5f * bx.z) * W;
            o.w = (bx.y + 0.5f * bx.w) * H;
            *(float4*)(out + 2 * NROWS + (size_t)br * 4) = o;
        }
    }

    // ---------- Phase 1: cos table (double) in the future-M1 region ----------
    double* tab = (double*)&smem[TAB_OFF];             // byte off 11776, 8B aligned
    for (int t = tid; t < 512; t += 256)
        tab[t] = cos((3.14159265358979323846 / 256.0) * (double)t);
    __syncthreads();

    // ---------- Phase 2: build Csub (bit-identical f64 math) + coef zero/scatter ----------
    {
        const double s0 = sqrt(1.0 / 128.0);
        for (int idx = tid; idx < KSUB * L; idx += 256) {
            const int u = idx >> 7, m = idx & 127;
            float v;
            if (u == 0) v = (float)s0;
            else        v = (float)(0.125 * tab[((2 * m + 1) * u) & 511]); // sqrt(2/128)=0.125
            smem[idx] = v;
        }
    }
    float* coef = &smem[COEF_OFF];
    // Zero only the complement of the scattered zigzag set (disjoint writes).
    for (int t = tid; t < KSUB * 24; t += 256) {
        const int u = t / 24, v = t - u * 24;
        const int s = u + v;
        if (v == 23 || s > 22 || (s == 22 && u < 20)) coef[t] = 0.0f;
    }
    {
        const int k = tid;                              // 256 threads = 256 coefs
        int s = 0;
        while ((s + 1) * (s + 2) / 2 <= k) ++s;         // diagonal index, s <= 22
        const int r = k - s * (s + 1) / 2;
        const int u  = (s & 1) ? r : (s - r);
        const int vv = (s & 1) ? (s - r) : r;
        coef[u * 24 + vv] = vecs[(size_t)br * NKEEP + k];
    }
    __syncthreads();                                    // tab dead from here

    // ---------- Part D: M1t[v][i] = sum_u Csub[u][i]*coef[u][v], float4 coef reads ----------
    float* M1 = &smem[M1_OFF];
    {
        const int i = tid & 127;
        float cs[KSUB];
        #pragma unroll
        for (int u = 0; u < KSUB; ++u) cs[u] = smem[u * L + i];

        if (tid < 128) {                                // v = 0..11
            float a[12];
            #pragma unroll
            for (int v = 0; v < 12; ++v) a[v] = 0.0f;
            #pragma unroll
            for (int u = 0; u < KSUB; ++u) {
                const float4 c0 = *(const float4*)&coef[u * 24 + 0];
                const float4 c1 = *(const float4*)&coef[u * 24 + 4];
                const float4 c2 = *(const float4*)&coef[u * 24 + 8];
                const float cu = cs[u];
                a[0]  += cu * c0.x; a[1]  += cu * c0.y; a[2]  += cu * c0.z; a[3]  += cu * c0.w;
                a[4]  += cu * c1.x; a[5]  += cu * c1.y; a[6]  += cu * c1.z; a[7]  += cu * c1.w;
                a[8]  += cu * c2.x; a[9]  += cu * c2.y; a[10] += cu * c2.z; a[11] += cu * c2.w;
            }
            #pragma unroll
            for (int v = 0; v < 12; ++v) M1[v * L + i] = a[v];
        } else {                                        // v = 12..22 (23 is padding, always 0)
            float a[11];
            #pragma unroll
            for (int v = 0; v < 11; ++v) a[v] = 0.0f;
            #pragma unroll
            for (int u = 0; u < KSUB; ++u) {
                const float4 c0 = *(const float4*)&coef[u * 24 + 12];
                const float4 c1 = *(const float4*)&coef[u * 24 + 16];
                const float4 c2 = *(const float4*)&coef[u * 24 + 20];
                const float cu = cs[u];
                a[0] += cu * c0.x; a[1] += cu * c0.y; a[2]  += cu * c0.z; a[3] += cu * c0.w;
                a[4] += cu * c1.x; a[5] += cu * c1.y; a[6]  += cu * c1.z; a[7] += cu * c1.w;
                a[8] += cu * c2.x; a[9] += cu * c2.y; a[10] += cu * c2.z;     // skip v=23
            }
            #pragma unroll
            for (int v = 0; v < 11; ++v) M1[(v + 12) * L + i] = a[v];
        }
    }
    __syncthreads();

    // ---------- Part E: re[i][j] = sum_v M1t[v][i]*Csub[v][j], 16x4 tile ----------
    const int tx = tid & 31, ty = tid >> 5;
    const int j0 = tx << 2, i0 = ty << 4;
    float acc[16][4];
    #pragma unroll
    for (int r = 0; r < 16; ++r)
        #pragma unroll
        for (int q = 0; q < 4; ++q) acc[r][q] = 0.0f;

    for (int v = 0; v < KSUB; ++v) {
        const float4 c = *(const float4*)&smem[v * L + j0];
        #pragma unroll
        for (int g = 0; g < 4; ++g) {
            const float4 m = *(const float4*)&M1[v * L + i0 + 4 * g];
            acc[4*g+0][0] += m.x * c.x; acc[4*g+0][1] += m.x * c.y;
            acc[4*g+0][2] += m.x * c.z; acc[4*g+0][3] += m.x * c.w;
            acc[4*g+1][0] += m.y * c.x; acc[4*g+1][1] += m.y * c.y;
            acc[4*g+1][2] += m.y * c.z; acc[4*g+1][3] += m.y * c.w;
            acc[4*g+2][0] += m.z * c.x; acc[4*g+2][1] += m.z * c.y;
            acc[4*g+2][2] += m.z * c.z; acc[4*g+2][3] += m.z * c.w;
            acc[4*g+3][0] += m.w * c.x; acc[4*g+3][1] += m.w * c.y;
            acc[4*g+3][2] += m.w * c.z; acc[4*g+3][3] += m.w * c.w;
        }
    }

    // ---------- min/max reduce -> threshold ----------
    float mn = acc[0][0], mx = acc[0][0];
    #pragma unroll
    for (int r = 0; r < 16; ++r)
        #pragma unroll
        for (int q = 0; q < 4; ++q) {
            mn = fminf(mn, acc[r][q]);
            mx = fmaxf(mx, acc[r][q]);
        }
    #pragma unroll
    for (int off = 32; off > 0; off >>= 1) {
        mn = fminf(mn, __shfl_xor(mn, off, 64));
        mx = fmaxf(mx, __shfl_xor(mx, off, 64));
    }
    const int w = tid >> 6;
    if ((tid & 63) == 0) { smem[RED_OFF + w] = mn; smem[RED_OFF + 4 + w] = mx; }
    __syncthreads();
    const float gmn = fminf(fminf(smem[RED_OFF + 0], smem[RED_OFF + 1]),
                            fminf(smem[RED_OFF + 2], smem[RED_OFF + 3]));
    const float gmx = fmaxf(fmaxf(smem[RED_OFF + 4], smem[RED_OFF + 5]),
                            fmaxf(smem[RED_OFF + 6], smem[RED_OFF + 7]));
    const float thr = (gmx + gmn) * 0.5f;

    // ---------- binarize + coalesced float4 stores ----------
    float* omask = out + 6 * NROWS + (size_t)br * (L * L);
    #pragma unroll
    for (int r = 0; r < 16; ++r) {
        float4 o;
        o.x = acc[r][0] > thr ? 1.0f : 0.0f;
        o.y = acc[r][1] > thr ? 1.0f : 0.0f;
        o.z = acc[r][2] > thr ? 1.0f : 0.0f;
        o.w = acc[r][3] > thr ? 1.0f : 0.0f;
        *(float4*)&omask[(i0 + r) * L + j0] = o;
    }
}

extern "C" void kernel_launch(void* const* d_in, const int* in_sizes, int n_in,
                              void* d_out, int out_size, void* d_ws, size_t ws_size,
                              hipStream_t stream)
{
    const float* logits = (const float*)d_in[0];
    const float* pboxes = (const float*)d_in[1];
    const float* vecs   = (const float*)d_in[2];
    const int*   tsz    = (const int*)d_in[3];
    float* out = (float*)d_out;
    (void)d_ws; (void)ws_size; (void)in_sizes; (void)n_in; (void)out_size;

    postproc_kernel<<<dim3(NROWS), dim3(256), 0, stream>>>(logits, pboxes, vecs, tsz, out);
}

// Round 6
// 187.113 us; speedup vs baseline: 1.2413x; 1.0206x over previous
//
#include <hip/hip_runtime.h>
#include <math.h>

#define NROWS 2400
#define NCLS  91
#define L     128
#define KSUB  23
#define NKEEP 256

// LDS float layout:
// [0, 2944)      Csub[23][128]
// [2944, 5888)   phase 1: double tab[512]  ([2944,3968))
//                phase 2+: M1t[23][128]
// [5888, 6440)   coef[23][24]
// [6440, 6456)   min/max reduce scratch (8 waves x 2)
#define TAB_OFF  2944
#define M1_OFF   2944
#define COEF_OFF 5888
#define RED_OFF  6440
#define SMEM_FLOATS 6456

__global__ void __launch_bounds__(512, 6)   // cap VGPR ~85; target natural <=64
postproc_kernel(const float* __restrict__ logits,
                const float* __restrict__ pboxes,
                const float* __restrict__ vecs,
                const int*   __restrict__ tsz,
                float* __restrict__ out)
{
    __shared__ float smem[SMEM_FLOATS];
    const int br  = blockIdx.x;
    const int tid = threadIdx.x;

    // ---------- Part A: scores / labels / boxes (wave 0 only, no barriers) ----------
    if (tid < 64) {
        const float* lrow = logits + (size_t)br * NCLS;
        float p = 1.0f / (1.0f + expf(-lrow[tid]));
        int   bi = tid;
        if (tid < NCLS - 64) {
            float p2 = 1.0f / (1.0f + expf(-lrow[tid + 64]));
            if (p2 > p) { p = p2; bi = tid + 64; }    // tie -> keep lower index
        }
        #pragma unroll
        for (int off = 32; off > 0; off >>= 1) {
            float po = __shfl_xor(p, off, 64);
            int   io = __shfl_xor(bi, off, 64);
            if (po > p || (po == p && io < bi)) { p = po; bi = io; }
        }
        if (tid == 0) {
            out[br] = p;
            out[NROWS + br] = (float)bi;
            const int b = br / 300;
            const float W = (float)tsz[2 * b + 1];
            const float H = (float)tsz[2 * b + 0];
            const float4 bx = *(const float4*)(pboxes + (size_t)br * 4);
            float4 o;
            o.x = (bx.x - 0.5f * bx.z) * W;
            o.y = (bx.y - 0.5f * bx.w) * H;
            o.z = (bx.x + 0.5f * bx.z) * W;
            o.w = (bx.y + 0.5f * bx.w) * H;
            *(float4*)(out + 2 * NROWS + (size_t)br * 4) = o;
        }
    }

    // ---------- Phase 1: cos table (double) in the future-M1 region ----------
    double* tab = (double*)&smem[TAB_OFF];
    if (tid < 512) tab[tid] = cos((3.14159265358979323846 / 256.0) * (double)tid);
    __syncthreads();

    // ---------- Phase 2: Csub build (bit-identical f64 math) + coef zero/scatter ----------
    {
        const double s0 = sqrt(1.0 / 128.0);
        for (int idx = tid; idx < KSUB * L; idx += 512) {
            const int u = idx >> 7, m = idx & 127;
            float v;
            if (u == 0) v = (float)s0;
            else        v = (float)(0.125 * tab[((2 * m + 1) * u) & 511]); // sqrt(2/128)=0.125
            smem[idx] = v;
        }
    }
    float* coef = &smem[COEF_OFF];
    for (int t = tid; t < KSUB * 24; t += 512) {
        const int u = t / 24, v = t - u * 24;
        const int s = u + v;
        if (v == 23 || s > 22 || (s == 22 && u < 20)) coef[t] = 0.0f;
    }
    if (tid < NKEEP) {
        const int k = tid;
        int s = 0;
        while ((s + 1) * (s + 2) / 2 <= k) ++s;
        const int r = k - s * (s + 1) / 2;
        const int u  = (s & 1) ? r : (s - r);
        const int vv = (s & 1) ? (s - r) : r;
        coef[u * 24 + vv] = vecs[(size_t)br * NKEEP + k];
    }
    __syncthreads();                                    // tab dead from here

    // ---------- Part D: M1t[v][i] = sum_u Csub[u][i]*coef[u][v] ----------
    // 512 threads: i = tid&127, v-group g = tid>>7 handles 6/6/6/5 v's.
    // Each M1 element: single thread, ascending-u FMA chain -> bit-identical.
    float* M1 = &smem[M1_OFF];
    {
        const int i = tid & 127;
        const int g = tid >> 7;                         // wave-uniform (waves 2g,2g+1)
        float cs[KSUB];
        #pragma unroll
        for (int u = 0; u < KSUB; ++u) cs[u] = smem[u * L + i];

        const int vbase = g * 6;                        // 0,6,12,18 (8B-aligned in coef)
        float a[6];
        #pragma unroll
        for (int v = 0; v < 6; ++v) a[v] = 0.0f;
        if (g < 3) {
            #pragma unroll
            for (int u = 0; u < KSUB; ++u) {
                const float2 c0 = *(const float2*)&coef[u * 24 + vbase + 0];
                const float2 c1 = *(const float2*)&coef[u * 24 + vbase + 2];
                const float2 c2 = *(const float2*)&coef[u * 24 + vbase + 4];
                const float cu = cs[u];
                a[0] += cu * c0.x; a[1] += cu * c0.y;
                a[2] += cu * c1.x; a[3] += cu * c1.y;
                a[4] += cu * c2.x; a[5] += cu * c2.y;
            }
            #pragma unroll
            for (int v = 0; v < 6; ++v) M1[(vbase + v) * L + i] = a[v];
        } else {
            #pragma unroll
            for (int u = 0; u < KSUB; ++u) {
                const float2 c0 = *(const float2*)&coef[u * 24 + 18];
                const float2 c1 = *(const float2*)&coef[u * 24 + 20];
                const float  c2 = coef[u * 24 + 22];
                const float cu = cs[u];
                a[0] += cu * c0.x; a[1] += cu * c0.y;
                a[2] += cu * c1.x; a[3] += cu * c1.y;
                a[4] += cu * c2;
            }
            #pragma unroll
            for (int v = 0; v < 5; ++v) M1[(18 + v) * L + i] = a[v];
        }
    }
    __syncthreads();

    // ---------- Part E: re[i][j] = sum_v M1t[v][i]*Csub[v][j], 8x4 tile ----------
    const int tx = tid & 31, iy = tid >> 5;             // iy in [0,16)
    const int j0 = tx << 2, i0 = iy << 3;
    float acc[8][4];
    #pragma unroll
    for (int r = 0; r < 8; ++r)
        #pragma unroll
        for (int q = 0; q < 4; ++q) acc[r][q] = 0.0f;

    for (int v = 0; v < KSUB; ++v) {
        const float4 c = *(const float4*)&smem[v * L + j0];
        #pragma unroll
        for (int g = 0; g < 2; ++g) {
            const float4 m = *(const float4*)&M1[v * L + i0 + 4 * g];
            acc[4*g+0][0] += m.x * c.x; acc[4*g+0][1] += m.x * c.y;
            acc[4*g+0][2] += m.x * c.z; acc[4*g+0][3] += m.x * c.w;
            acc[4*g+1][0] += m.y * c.x; acc[4*g+1][1] += m.y * c.y;
            acc[4*g+1][2] += m.y * c.z; acc[4*g+1][3] += m.y * c.w;
            acc[4*g+2][0] += m.z * c.x; acc[4*g+2][1] += m.z * c.y;
            acc[4*g+2][2] += m.z * c.z; acc[4*g+2][3] += m.z * c.w;
            acc[4*g+3][0] += m.w * c.x; acc[4*g+3][1] += m.w * c.y;
            acc[4*g+3][2] += m.w * c.z; acc[4*g+3][3] += m.w * c.w;
        }
    }

    // ---------- min/max reduce -> threshold ----------
    float mn = acc[0][0], mx = acc[0][0];
    #pragma unroll
    for (int r = 0; r < 8; ++r)
        #pragma unroll
        for (int q = 0; q < 4; ++q) {
            mn = fminf(mn, acc[r][q]);
            mx = fmaxf(mx, acc[r][q]);
        }
    #pragma unroll
    for (int off = 32; off > 0; off >>= 1) {
        mn = fminf(mn, __shfl_xor(mn, off, 64));
        mx = fmaxf(mx, __shfl_xor(mx, off, 64));
    }
    const int w = tid >> 6;                             // wave id, 0..7
    if ((tid & 63) == 0) { smem[RED_OFF + w] = mn; smem[RED_OFF + 8 + w] = mx; }
    __syncthreads();
    float gmn = smem[RED_OFF + 0], gmx = smem[RED_OFF + 8];
    #pragma unroll
    for (int k = 1; k < 8; ++k) {
        gmn = fminf(gmn, smem[RED_OFF + k]);
        gmx = fmaxf(gmx, smem[RED_OFF + 8 + k]);
    }
    const float thr = (gmx + gmn) * 0.5f;

    // ---------- binarize + coalesced float4 stores ----------
    float* omask = out + 6 * NROWS + (size_t)br * (L * L);
    #pragma unroll
    for (int r = 0; r < 8; ++r) {
        float4 o;
        o.x = acc[r][0] > thr ? 1.0f : 0.0f;
        o.y = acc[r][1] > thr ? 1.0f : 0.0f;
        o.z = acc[r][2] > thr ? 1.0f : 0.0f;
        o.w = acc[r][3] > thr ? 1.0f : 0.0f;
        *(float4*)&omask[(i0 + r) * L + j0] = o;
    }
}

extern "C" void kernel_launch(void* const* d_in, const int* in_sizes, int n_in,
                              void* d_out, int out_size, void* d_ws, size_t ws_size,
                              hipStream_t stream)
{
    const float* logits = (const float*)d_in[0];
    const float* pboxes = (const float*)d_in[1];
    const float* vecs   = (const float*)d_in[2];
    const int*   tsz    = (const int*)d_in[3];
    float* out = (float*)d_out;
    (void)d_ws; (void)ws_size; (void)in_sizes; (void)n_in; (void)out_size;

    postproc_kernel<<<dim3(NROWS), dim3(512), 0, stream>>>(logits, pboxes, vecs, tsz, out);
}